// Round 8
// baseline (4135.202 us; speedup 1.0000x reference)
//
#include <hip/hip_runtime.h>
#include <cstdint>
#include <cstddef>

typedef short short8 __attribute__((ext_vector_type(8)));
typedef short short4v __attribute__((ext_vector_type(4)));
typedef float f32x16 __attribute__((ext_vector_type(16)));
typedef float f32x4 __attribute__((ext_vector_type(4)));

__device__ inline unsigned short bf16_rne(float x) {
    unsigned u = __float_as_uint(x);
    unsigned r = u + 0x7FFFu + ((u >> 16) & 1u);
    return (unsigned short)(r >> 16);
}
__device__ inline float bf16_to_f(unsigned short h) {
    return __uint_as_float(((unsigned)h) << 16);
}

// ---------------- weight reorders ----------------
// conv1_w (256,64,9,9) -> MFMA-fragment-order split-bf16 planes (32x32x16):
// wf[(ksg*8 + nc)*1024 u16]: [0..511]=hi frag, [512..1023]=lo frag
// ksg = cc*81 + tap (cc = 16-ci chunk) ; ci = cc*16 + (l>>5)*8 + j ; co = nc*32 + (l&31)
__global__ void reorder_wf_kernel(const float* __restrict__ w, unsigned short* __restrict__ wf) {
    int idx = blockIdx.x * 256 + threadIdx.x;      // over 324*8*64*8 = 1,327,104
    if (idx >= 324 * 8 * 64 * 8) return;
    int j   = idx & 7;
    int l   = (idx >> 3) & 63;
    int nc  = (idx >> 9) & 7;
    int ksg = idx >> 12;                           // 0..323
    int cc  = ksg / 81;
    int tap = ksg - cc * 81;
    int ci  = cc * 16 + ((l >> 5) << 3) + j;
    int co  = nc * 32 + (l & 31);
    float v = w[(co * 64 + ci) * 81 + tap];
    unsigned short hi = bf16_rne(v);
    unsigned short lo = bf16_rne(v - bf16_to_f(hi));
    size_t base = ((size_t)(ksg * 8 + nc)) * 1024;
    wf[base + l * 8 + j]       = hi;
    wf[base + 512 + l * 8 + j] = lo;
}

// pc_w (48,256,8,8) -> MFMA-fragment-order split-bf16 (16x16x32):
// dims [cc=8][tap=64][ct=3][plane=2][l=64][j=8] u16
__global__ void reorder_pcwf_kernel(const float* __restrict__ w, unsigned short* __restrict__ wf) {
    int idx = blockIdx.x * 256 + threadIdx.x;      // over 1,572,864
    if (idx >= 1572864) return;
    int j     = idx & 7;
    int l     = (idx >> 3) & 63;
    int plane = (idx >> 9) & 1;
    int rest  = idx >> 10;
    int ct    = rest % 3;
    int rest2 = rest / 3;
    int tap   = rest2 & 63;
    int cc    = rest2 >> 6;
    int co = ct * 16 + (l & 15);
    int ci = cc * 32 + ((l >> 4) << 3) + j;
    float v = w[((size_t)co * 256 + ci) * 64 + tap];
    unsigned short hi = bf16_rne(v);
    unsigned short out = plane ? bf16_rne(v - bf16_to_f(hi)) : hi;
    wf[idx] = out;
}

// ---------------- conv1 via split-bf16 MFMA ----------------
// per image: M=196px (7 tiles of 32, padded), N=256co, K=5184 (4 ci-chunks x 81 taps x 16)
// block = 512 thr = 8 waves = 2 M-groups (4/3 m-tiles) x 4 N-groups (2 cols of 32 co)
// LDS: Xs[484][40] u16 = 38,720 B ; A-frags b128, pass-major MFMA (no dep chains)
#define RS 40

template<int MTC>
__device__ __forceinline__ void conv1_body(
    unsigned short* Xs, const float* __restrict__ x,
    const unsigned short* __restrict__ wf, const float* __restrict__ b1,
    float* __restrict__ c1o, int bg, int il, int t, int mtbase)
{
    const int l = t & 63;
    const int w = t >> 6;
    const int ncg = w & 3;
    const int lane31 = l & 31;
    const int kg = l >> 5;
    const int c0a = (ncg * 2) * 32 + lane31;
    const int c1a = c0a + 32;
    const float biasA = b1[c0a];
    const float biasB = b1[c1a];

    int am[MTC];
#pragma unroll
    for (int i = 0; i < MTC; ++i) {
        int p = (mtbase + i) * 32 + lane31;
        int pp = (p < 196) ? p : 0;      // clamp pad rows into valid LDS
        int oh = pp / 14, ow = pp - oh * 14;
        am[i] = (oh * 22 + ow) * RS + kg * 8;
    }
    const char* wfb = (const char*)wf;
    const int boffA = (ncg * 2) * 2048 + l * 16;
    const int boffB = boffA + 2048;

    const int sidx = t >> 2;          // staging pixel row (+128/round)
    const int sblk = t & 3;           // staging ci block (4 ci)

    f32x16 acc[MTC][2];
#pragma unroll
    for (int i = 0; i < MTC; ++i) { acc[i][0] = (f32x16)(0.f); acc[i][1] = (f32x16)(0.f); }

    // prologue: stage cc=0 (gather-transpose, vector LDS writes)
#pragma unroll
    for (int r = 0; r < 4; ++r) {
        int s = sidx + r * 128;
        if (s < 484) {
            short4v hv, lv;
#pragma unroll
            for (int e = 0; e < 4; ++e) {
                float xv = x[((size_t)bg * 64 + sblk * 4 + e) * 484 + s];
                unsigned short hi = bf16_rne(xv);
                hv[e] = (short)hi;
                lv[e] = (short)bf16_rne(xv - bf16_to_f(hi));
            }
            *(short4v*)(Xs + s * RS + sblk * 4)      = hv;
            *(short4v*)(Xs + s * RS + 16 + sblk * 4) = lv;
        }
    }
    __syncthreads();

    for (int cc = 0; cc < 4; ++cc) {
        // issue next chunk's global loads early; latency hides under the 81 taps
        float vx[4][4];
        if (cc < 3) {
#pragma unroll
            for (int r = 0; r < 4; ++r) {
                int s = sidx + r * 128;
                if (s < 484) {
#pragma unroll
                    for (int e = 0; e < 4; ++e)
                        vx[r][e] = x[((size_t)bg * 64 + (cc + 1) * 16 + sblk * 4 + e) * 484 + s];
                }
            }
        }

        const int ksgb = cc * 81;
        const char* bp0 = wfb + (size_t)ksgb * 16384;
        short8 bhA0 = *(const short8*)(bp0 + boffA);
        short8 blA0 = *(const short8*)(bp0 + 1024 + boffA);
        short8 bhB0 = *(const short8*)(bp0 + boffB);
        short8 blB0 = *(const short8*)(bp0 + 1024 + boffB);

        for (int tap = 0; tap < 81; ++tap) {
            // prefetch next tap's B frags (L2-resident)
            int kn = ksgb + tap + 1; if (kn > 323) kn = 323;
            const char* bpn = wfb + (size_t)kn * 16384;
            short8 bhA1 = *(const short8*)(bpn + boffA);
            short8 blA1 = *(const short8*)(bpn + 1024 + boffA);
            short8 bhB1 = *(const short8*)(bpn + boffB);
            short8 blB1 = *(const short8*)(bpn + 1024 + boffB);

            const int kh = tap / 9, kw = tap - kh * 9;
            const int toff = (kh * 22 + kw) * RS;
            short8 Ah[MTC], Al[MTC];
#pragma unroll
            for (int i = 0; i < MTC; ++i) {
                const int a = am[i] + toff;
                Ah[i] = *(const short8*)(Xs + a);
                Al[i] = *(const short8*)(Xs + a + 16);
            }
            // pass-major: consecutive MFMAs hit different accumulators
#pragma unroll
            for (int i = 0; i < MTC; ++i) acc[i][0] = __builtin_amdgcn_mfma_f32_32x32x16_bf16(Ah[i], bhA0, acc[i][0], 0, 0, 0);
#pragma unroll
            for (int i = 0; i < MTC; ++i) acc[i][1] = __builtin_amdgcn_mfma_f32_32x32x16_bf16(Ah[i], bhB0, acc[i][1], 0, 0, 0);
#pragma unroll
            for (int i = 0; i < MTC; ++i) acc[i][0] = __builtin_amdgcn_mfma_f32_32x32x16_bf16(Al[i], bhA0, acc[i][0], 0, 0, 0);
#pragma unroll
            for (int i = 0; i < MTC; ++i) acc[i][1] = __builtin_amdgcn_mfma_f32_32x32x16_bf16(Al[i], bhB0, acc[i][1], 0, 0, 0);
#pragma unroll
            for (int i = 0; i < MTC; ++i) acc[i][0] = __builtin_amdgcn_mfma_f32_32x32x16_bf16(Ah[i], blA0, acc[i][0], 0, 0, 0);
#pragma unroll
            for (int i = 0; i < MTC; ++i) acc[i][1] = __builtin_amdgcn_mfma_f32_32x32x16_bf16(Ah[i], blB0, acc[i][1], 0, 0, 0);
#pragma unroll
            for (int i = 0; i < MTC; ++i) acc[i][0] = __builtin_amdgcn_mfma_f32_32x32x16_bf16(Al[i], blA0, acc[i][0], 0, 0, 0);
#pragma unroll
            for (int i = 0; i < MTC; ++i) acc[i][1] = __builtin_amdgcn_mfma_f32_32x32x16_bf16(Al[i], blB0, acc[i][1], 0, 0, 0);

            bhA0 = bhA1; blA0 = blA1; bhB0 = bhB1; blB0 = blB1;
        }

        if (cc < 3) {
            __syncthreads();          // all waves done reading Xs for this cc
#pragma unroll
            for (int r = 0; r < 4; ++r) {
                int s = sidx + r * 128;
                if (s < 484) {
                    short4v hv, lv;
#pragma unroll
                    for (int e = 0; e < 4; ++e) {
                        float xv = vx[r][e];
                        unsigned short hi = bf16_rne(xv);
                        hv[e] = (short)hi;
                        lv[e] = (short)bf16_rne(xv - bf16_to_f(hi));
                    }
                    *(short4v*)(Xs + s * RS + sblk * 4)      = hv;
                    *(short4v*)(Xs + s * RS + 16 + sblk * 4) = lv;
                }
            }
            __syncthreads();
        }
    }

    // epilogue: bias + relu, NHWC store (C/D: col=lane&31, row=(r&3)+8*(r>>2)+4*(lane>>5))
#pragma unroll
    for (int i = 0; i < MTC; ++i) {
#pragma unroll
        for (int r = 0; r < 16; ++r) {
            int p = (mtbase + i) * 32 + (r & 3) + ((r >> 2) << 3) + kg * 4;
            if (p < 196) {
                size_t row = ((size_t)il * 196 + p) * 256;
                c1o[row + c0a] = fmaxf(acc[i][0][r] + biasA, 0.f);
                c1o[row + c1a] = fmaxf(acc[i][1][r] + biasB, 0.f);
            }
        }
    }
}

__global__ __launch_bounds__(512, 1) void conv1_mfma_kernel(
    const float* __restrict__ x, const unsigned short* __restrict__ wf,
    const float* __restrict__ b1, float* __restrict__ c1o, int c0)
{
    __shared__ __align__(16) unsigned short Xs[484 * RS];
    const int t  = threadIdx.x;
    const int il = blockIdx.x;
    const int bg = c0 + il;
    if ((t >> 6) < 4) conv1_body<4>(Xs, x, wf, b1, c1o, bg, il, t, 0);
    else              conv1_body<3>(Xs, x, wf, b1, c1o, bg, il, t, 4);
}

// ---------------- primary caps conv via split-bf16 MFMA ----------------
#define PC_RS 36

__global__ __launch_bounds__(256, 2) void pc_mfma_kernel(
    const float* __restrict__ c1o, const unsigned short* __restrict__ pcwf,
    const float* __restrict__ pcb, float* __restrict__ pco)
{
    __shared__ unsigned short Xh[196 * PC_RS];
    __shared__ unsigned short Xl[196 * PC_RS];
    const int t  = threadIdx.x;
    const int l  = t & 63;
    const int w  = t >> 6;
    const int il = blockIdx.x;
    const int pos = l & 15;           // A row
    const int kg  = l >> 4;           // k-group 0..3
    const int oh = pos >> 2, ow = pos & 3;
    const char* wb = (const char*)pcwf;

    f32x4 acc0 = (f32x4)(0.f), acc1 = (f32x4)(0.f), acc2 = (f32x4)(0.f);

    for (int cc = 0; cc < 8; ++cc) {
        __syncthreads();
        for (int q = t; q < 1568; q += 256) {          // 196 px * 8 float4
            int p  = q >> 3;
            int c4 = (q & 7) << 2;
            const float4 v = *(const float4*)(c1o + ((size_t)il * 196 + p) * 256 + cc * 32 + c4);
            short4v hv, lv;
#pragma unroll
            for (int e = 0; e < 4; ++e) {
                float xv = ((const float*)&v)[e];
                unsigned short hi = bf16_rne(xv);
                hv[e] = (short)hi;
                lv[e] = (short)bf16_rne(xv - bf16_to_f(hi));
            }
            *(short4v*)(Xh + p * PC_RS + c4) = hv;
            *(short4v*)(Xl + p * PC_RS + c4) = lv;
        }
        __syncthreads();

        short8 Bh0[3], Bl0[3], Bh1[3], Bl1[3];
        {
            const char* bp = wb + ((size_t)(cc * 64 + w) * 6) * 1024 + l * 16;
#pragma unroll
            for (int ct = 0; ct < 3; ++ct) {
                Bh0[ct] = *(const short8*)(bp + ct * 2048);
                Bl0[ct] = *(const short8*)(bp + ct * 2048 + 1024);
            }
        }
        for (int tt = 0; tt < 16; ++tt) {
            const int tap = tt * 4 + w;
            const int tapn = (tt == 15) ? tap : (tap + 4);
            const char* bpn = wb + ((size_t)(cc * 64 + tapn) * 6) * 1024 + l * 16;
#pragma unroll
            for (int ct = 0; ct < 3; ++ct) {
                Bh1[ct] = *(const short8*)(bpn + ct * 2048);
                Bl1[ct] = *(const short8*)(bpn + ct * 2048 + 1024);
            }
            const int kh = tap >> 3, kw = tap & 7;
            const int pix = (2 * oh + kh) * 14 + (2 * ow + kw);
            const int a = pix * PC_RS + kg * 8;
            short4v h0 = *(const short4v*)(Xh + a);
            short4v h1 = *(const short4v*)(Xh + a + 4);
            short4v q0 = *(const short4v*)(Xl + a);
            short4v q1 = *(const short4v*)(Xl + a + 4);
            short8 Ah = __builtin_shufflevector(h0, h1, 0, 1, 2, 3, 4, 5, 6, 7);
            short8 Al = __builtin_shufflevector(q0, q1, 0, 1, 2, 3, 4, 5, 6, 7);

            acc0 = __builtin_amdgcn_mfma_f32_16x16x32_bf16(Ah, Bh0[0], acc0, 0, 0, 0);
            acc0 = __builtin_amdgcn_mfma_f32_16x16x32_bf16(Ah, Bl0[0], acc0, 0, 0, 0);
            acc0 = __builtin_amdgcn_mfma_f32_16x16x32_bf16(Al, Bh0[0], acc0, 0, 0, 0);
            acc0 = __builtin_amdgcn_mfma_f32_16x16x32_bf16(Al, Bl0[0], acc0, 0, 0, 0);
            acc1 = __builtin_amdgcn_mfma_f32_16x16x32_bf16(Ah, Bh0[1], acc1, 0, 0, 0);
            acc1 = __builtin_amdgcn_mfma_f32_16x16x32_bf16(Ah, Bl0[1], acc1, 0, 0, 0);
            acc1 = __builtin_amdgcn_mfma_f32_16x16x32_bf16(Al, Bh0[1], acc1, 0, 0, 0);
            acc1 = __builtin_amdgcn_mfma_f32_16x16x32_bf16(Al, Bl0[1], acc1, 0, 0, 0);
            acc2 = __builtin_amdgcn_mfma_f32_16x16x32_bf16(Ah, Bh0[2], acc2, 0, 0, 0);
            acc2 = __builtin_amdgcn_mfma_f32_16x16x32_bf16(Ah, Bl0[2], acc2, 0, 0, 0);
            acc2 = __builtin_amdgcn_mfma_f32_16x16x32_bf16(Al, Bh0[2], acc2, 0, 0, 0);
            acc2 = __builtin_amdgcn_mfma_f32_16x16x32_bf16(Al, Bl0[2], acc2, 0, 0, 0);
#pragma unroll
            for (int ct = 0; ct < 3; ++ct) { Bh0[ct] = Bh1[ct]; Bl0[ct] = Bl1[ct]; }
        }
    }

    __syncthreads();
    float* R = (float*)Xh;
#pragma unroll
    for (int ct = 0; ct < 3; ++ct) {
        f32x4 a = (ct == 0) ? acc0 : (ct == 1) ? acc1 : acc2;
#pragma unroll
        for (int r = 0; r < 4; ++r)
            R[(((w * 3 + ct) * 64) + l) * 4 + r] = a[r];
    }
    __syncthreads();
    for (int idx = t; idx < 768; idx += 256) {
        int pp = idx & 15, co = idx >> 4;
        int ct = co >> 4, col = co & 15;
        int lane = ((pp >> 2) << 4) | col, reg = pp & 3;
        float s = 0.f;
#pragma unroll
        for (int w4 = 0; w4 < 4; ++w4)
            s += R[(((w4 * 3 + ct) * 64) + lane) * 4 + reg];
        pco[(size_t)il * 768 + idx] = s + pcb[co];
    }
}

// ---------------- capsule squash + u_hat + routing + logits + mask ----------------
__global__ __launch_bounds__(64) void caps_kernel(
    const float* __restrict__ pco, const float* __restrict__ Wd,
    float* __restrict__ logits_out, float* __restrict__ hbuf, int c0) {
    __shared__ float u_s[96][8];
    __shared__ float uh[2][96][16];
    __shared__ float vv[2][16];
    __shared__ float cc2[2][96];
    __shared__ float lg_s[2];
    const int t = threadIdx.x;
    const int il = blockIdx.x;

    for (int cap = t; cap < 96; cap += 64) {
        float xr[8];
        float n2 = 0.f;
#pragma unroll
        for (int k = 0; k < 8; ++k) {
            xr[k] = pco[(size_t)il * 768 + cap * 8 + k];
            n2 = fmaf(xr[k], xr[k], n2);
        }
        float nr = sqrtf(n2);
        float sc = tanhf(nr) / (nr + 1e-8f);
#pragma unroll
        for (int k = 0; k < 8; ++k) u_s[cap][k] = xr[k] * sc;
    }
    __syncthreads();
    for (int j = t; j < 3072; j += 64) {
        int d = j & 15;
        int oi = j >> 4;           // o*96 + i
        int i = oi % 96;
        int o = oi / 96;
        float acc = 0.f;
#pragma unroll
        for (int k = 0; k < 8; ++k)
            acc = fmaf(Wd[(size_t)j * 8 + k], u_s[i][k], acc);
        uh[o][i][d] = acc;
    }
    __syncthreads();
    const int o = t >> 4, d = t & 15;
    if (t < 32) {
        float s = 0.f;
        for (int i = 0; i < 96; ++i) s += 0.5f * uh[o][i][d];
        float n2 = s * s;
        n2 += __shfl_xor(n2, 1); n2 += __shfl_xor(n2, 2);
        n2 += __shfl_xor(n2, 4); n2 += __shfl_xor(n2, 8);
        float nr = sqrtf(n2);
        vv[o][d] = tanhf(nr) * s / (nr + 1e-8f);
    }
    __syncthreads();
    for (int j = t; j < 192; j += 64) {
        int oo = j / 96, ii = j - oo * 96;
        float bsum = 0.f;
#pragma unroll
        for (int dd = 0; dd < 16; ++dd)
            bsum = fmaf(uh[oo][ii][dd], vv[oo][dd], bsum);
        cc2[oo][ii] = bsum;
    }
    __syncthreads();
    for (int ii = t; ii < 96; ii += 64) {
        float b0 = cc2[0][ii], b1v = cc2[1][ii];
        float m = fmaxf(b0, b1v);
        float e0 = expf(b0 - m), e1 = expf(b1v - m);
        float inv = 1.f / (e0 + e1);
        cc2[0][ii] = e0 * inv;
        cc2[1][ii] = e1 * inv;
    }
    __syncthreads();
    if (t < 32) {
        float s = 0.f;
        for (int i = 0; i < 96; ++i) s = fmaf(cc2[o][i], uh[o][i][d], s);
        float n2 = s * s;
        n2 += __shfl_xor(n2, 1); n2 += __shfl_xor(n2, 2);
        n2 += __shfl_xor(n2, 4); n2 += __shfl_xor(n2, 8);
        float nr = sqrtf(n2);
        float v = tanhf(nr) * s / (nr + 1e-8f);
        float n2v = v * v;
        n2v += __shfl_xor(n2v, 1); n2v += __shfl_xor(n2v, 2);
        n2v += __shfl_xor(n2v, 4); n2v += __shfl_xor(n2v, 8);
        vv[o][d] = v;
        if (d == 0) {
            float lg = sqrtf(n2v);
            lg_s[o] = lg;
            logits_out[(size_t)(c0 + il) * 2 + o] = lg;
        }
    }
    __syncthreads();
    if (t < 32) {
        int ostar = (lg_s[1] > lg_s[0]) ? 1 : 0;
        hbuf[(size_t)il * 32 + t] = (o == ostar) ? vv[o][d] : 0.f;
    }
}

// ---------------- decoder FC: out = act(in @ W^T + b) ----------------
__global__ __launch_bounds__(256) void fc_kernel(
    const float* __restrict__ in, const float* __restrict__ W,
    const float* __restrict__ bias, float* __restrict__ out,
    int M, int N, int K, int act) {
    __shared__ float As[64][33];
    __shared__ float Bs[64][33];
    const int t = threadIdx.x;
    const int m0 = blockIdx.x * 64, n0 = blockIdx.y * 64;
    const int tn = t & 15, tm = t >> 4;
    float acc[4][4];
#pragma unroll
    for (int i = 0; i < 4; ++i)
#pragma unroll
        for (int j = 0; j < 4; ++j) acc[i][j] = 0.f;
    const int rr = t >> 2, c8 = (t & 3) * 8;
    for (int kc = 0; kc < K; kc += 32) {
        __syncthreads();
        const int mrow = m0 + rr;
#pragma unroll
        for (int q = 0; q < 8; ++q) {
            As[rr][c8 + q] = (mrow < M) ? in[(size_t)mrow * K + kc + c8 + q] : 0.f;
            Bs[rr][c8 + q] = W[(size_t)(n0 + rr) * K + kc + c8 + q];
        }
        __syncthreads();
#pragma unroll
        for (int k = 0; k < 32; ++k) {
            float av[4], bv[4];
#pragma unroll
            for (int i = 0; i < 4; ++i) av[i] = As[tm * 4 + i][k];
#pragma unroll
            for (int j = 0; j < 4; ++j) bv[j] = Bs[tn * 4 + j][k];
#pragma unroll
            for (int i = 0; i < 4; ++i)
#pragma unroll
                for (int j = 0; j < 4; ++j) acc[i][j] = fmaf(av[i], bv[j], acc[i][j]);
        }
    }
#pragma unroll
    for (int i = 0; i < 4; ++i) {
        int m = m0 + tm * 4 + i;
        if (m < M) {
#pragma unroll
            for (int j = 0; j < 4; ++j) {
                int nn = n0 + tn * 4 + j;
                float v = acc[i][j] + bias[nn];
                if (act == 0) v = fmaxf(v, 0.f);
                else v = 1.f / (1.f + expf(-v));
                out[(size_t)m * N + nn] = v;
            }
        }
    }
}

// ---------------- host ----------------
extern "C" void kernel_launch(void* const* d_in, const int* in_sizes, int n_in,
                              void* d_out, int out_size, void* d_ws, size_t ws_size,
                              hipStream_t stream) {
    const float* x    = (const float*)d_in[0];
    const float* w1   = (const float*)d_in[1];
    const float* b1   = (const float*)d_in[2];
    const float* pcw  = (const float*)d_in[3];
    const float* pcb  = (const float*)d_in[4];
    const float* Wd   = (const float*)d_in[5];
    const float* dw1  = (const float*)d_in[6];
    const float* db1  = (const float*)d_in[7];
    const float* dw2  = (const float*)d_in[8];
    const float* db2  = (const float*)d_in[9];
    const float* dw3  = (const float*)d_in[10];
    const float* db3  = (const float*)d_in[11];
    float* out = (float*)d_out;

    const int B = 2048;
    float* ws = (float*)d_ws;
    unsigned short* wf = (unsigned short*)ws;                // 2,654,208 u16
    unsigned short* pcwf = (unsigned short*)(ws + 1327104);  // 1,572,864 u16
    float* dyn  = ws + 1327104 + 786432;

    const long long base_floats = 1327104LL + 786432LL;
    const long long per_img = 50176 + 768 + 32 + 512 + 1024;   // 52,512 floats/img
    long long avail = (long long)(ws_size / 4) - base_floats;
    int CH;
    if (avail < per_img) CH = 1;
    else CH = (int)(avail / per_img);
    if (CH > B) CH = B;

    reorder_wf_kernel<<<(324 * 8 * 64 * 8 + 255) / 256, 256, 0, stream>>>(w1, wf);
    reorder_pcwf_kernel<<<(1572864 + 255) / 256, 256, 0, stream>>>(pcw, pcwf);

    float* c1o  = dyn;
    float* pco  = c1o  + (size_t)CH * 50176;
    float* hbuf = pco  + (size_t)CH * 768;
    float* h1   = hbuf + (size_t)CH * 32;
    float* h2   = h1   + (size_t)CH * 512;

    for (int c0 = 0; c0 < B; c0 += CH) {
        int n = B - c0; if (n > CH) n = CH;
        conv1_mfma_kernel<<<n, 512, 0, stream>>>(x, wf, b1, c1o, c0);
        pc_mfma_kernel<<<n, 256, 0, stream>>>(c1o, pcwf, pcb, pco);
        caps_kernel<<<n, 64, 0, stream>>>(pco, Wd, out, hbuf, c0);
        fc_kernel<<<dim3((n + 63) / 64, 8),  256, 0, stream>>>(hbuf, dw1, db1, h1, n, 512, 32, 0);
        fc_kernel<<<dim3((n + 63) / 64, 16), 256, 0, stream>>>(h1,   dw2, db2, h2, n, 1024, 512, 0);
        fc_kernel<<<dim3((n + 63) / 64, 4),  256, 0, stream>>>(h2,   dw3, db3, out + 4096 + (size_t)c0 * 256, n, 256, 1024, 1);
    }
}

// Round 9
// 4089.440 us; speedup vs baseline: 1.0112x; 1.0112x over previous
//
#include <hip/hip_runtime.h>
#include <cstdint>
#include <cstddef>

typedef short short8 __attribute__((ext_vector_type(8)));
typedef short short4v __attribute__((ext_vector_type(4)));
typedef float f32x16 __attribute__((ext_vector_type(16)));
typedef float f32x4 __attribute__((ext_vector_type(4)));

__device__ inline unsigned short bf16_rne(float x) {
    unsigned u = __float_as_uint(x);
    unsigned r = u + 0x7FFFu + ((u >> 16) & 1u);
    return (unsigned short)(r >> 16);
}
__device__ inline float bf16_to_f(unsigned short h) {
    return __uint_as_float(((unsigned)h) << 16);
}

// ---------------- weight reorders ----------------
// conv1_w (256,64,9,9) -> MFMA-fragment-order split-bf16 planes (32x32x16):
// wf[(ksg*8 + nc)*1024 u16]: [0..511]=hi frag, [512..1023]=lo frag
// ksg = cc*81 + tap (cc = 16-ci chunk) ; ci = cc*16 + (l>>5)*8 + j ; co = nc*32 + (l&31)
__global__ void reorder_wf_kernel(const float* __restrict__ w, unsigned short* __restrict__ wf) {
    int idx = blockIdx.x * 256 + threadIdx.x;      // over 324*8*64*8 = 1,327,104
    if (idx >= 324 * 8 * 64 * 8) return;
    int j   = idx & 7;
    int l   = (idx >> 3) & 63;
    int nc  = (idx >> 9) & 7;
    int ksg = idx >> 12;                           // 0..323
    int cc  = ksg / 81;
    int tap = ksg - cc * 81;
    int ci  = cc * 16 + ((l >> 5) << 3) + j;
    int co  = nc * 32 + (l & 31);
    float v = w[(co * 64 + ci) * 81 + tap];
    unsigned short hi = bf16_rne(v);
    unsigned short lo = bf16_rne(v - bf16_to_f(hi));
    size_t base = ((size_t)(ksg * 8 + nc)) * 1024;
    wf[base + l * 8 + j]       = hi;
    wf[base + 512 + l * 8 + j] = lo;
}

// pc_w (48,256,8,8) -> MFMA-fragment-order split-bf16 (16x16x32):
// dims [cc=8][tap=64][ct=3][plane=2][l=64][j=8] u16
__global__ void reorder_pcwf_kernel(const float* __restrict__ w, unsigned short* __restrict__ wf) {
    int idx = blockIdx.x * 256 + threadIdx.x;      // over 1,572,864
    if (idx >= 1572864) return;
    int j     = idx & 7;
    int l     = (idx >> 3) & 63;
    int plane = (idx >> 9) & 1;
    int rest  = idx >> 10;
    int ct    = rest % 3;
    int rest2 = rest / 3;
    int tap   = rest2 & 63;
    int cc    = rest2 >> 6;
    int co = ct * 16 + (l & 15);
    int ci = cc * 32 + ((l >> 4) << 3) + j;
    float v = w[((size_t)co * 256 + ci) * 64 + tap];
    unsigned short hi = bf16_rne(v);
    unsigned short out = plane ? bf16_rne(v - bf16_to_f(hi)) : hi;
    wf[idx] = out;
}

// ---------------- conv1 via split-bf16 MFMA ----------------
// per image: M=196px (7 tiles of 32, padded), N=256co, K=5184 (4 ci-chunks x 81 taps x 16)
// grid = 2 blocks/image (co-halves); block = 512 thr = 8 waves = 2 mgroups x 4 ncols
// wave tile = {4|3} m-tiles x 32 co -> acc 64/48 AGPR ; launch_bounds(512,4) pins <=128 regs
// LDS: Xs[484][40] u16 = 38,720 B -> 2 blocks/CU -> 16 waves/CU
#define RS 40

template<int MTC>
__device__ __forceinline__ void conv1_body(
    unsigned short* Xs, const float* __restrict__ x,
    const unsigned short* __restrict__ wf, const float* __restrict__ b1,
    float* __restrict__ c1o, int bg, int il, int t, int mtbase, int ncol)
{
    const int l = t & 63;
    const int lane31 = l & 31;
    const int kg = l >> 5;
    const int co = ncol * 32 + lane31;
    const float bias = b1[co];

    int am[MTC];
#pragma unroll
    for (int i = 0; i < MTC; ++i) {
        int p = (mtbase + i) * 32 + lane31;
        int pp = (p < 196) ? p : 0;      // clamp pad rows into valid LDS
        int oh = pp / 14, ow = pp - oh * 14;
        am[i] = (oh * 22 + ow) * RS + kg * 8;
    }
    const char* wfb = (const char*)wf;
    const int boff = ncol * 2048 + l * 16;

    const int sidx = t >> 2;          // staging pixel row (+128/round)
    const int sblk = t & 3;           // staging ci block (4 ci)

    f32x16 acc[MTC];
#pragma unroll
    for (int i = 0; i < MTC; ++i) acc[i] = (f32x16)(0.f);

    for (int cc = 0; cc < 4; ++cc) {
        // stage 16-ci chunk: gather-transpose, vector LDS writes (direct, no reg prefetch)
        if (cc > 0) __syncthreads();       // all waves done reading previous chunk
#pragma unroll
        for (int r = 0; r < 4; ++r) {
            int s = sidx + r * 128;
            if (s < 484) {
                short4v hv, lv;
#pragma unroll
                for (int e = 0; e < 4; ++e) {
                    float xv = x[((size_t)bg * 64 + cc * 16 + sblk * 4 + e) * 484 + s];
                    unsigned short hi = bf16_rne(xv);
                    hv[e] = (short)hi;
                    lv[e] = (short)bf16_rne(xv - bf16_to_f(hi));
                }
                *(short4v*)(Xs + s * RS + sblk * 4)      = hv;
                *(short4v*)(Xs + s * RS + 16 + sblk * 4) = lv;
            }
        }
        __syncthreads();

        const int ksgb = cc * 81;
        const char* bp0 = wfb + (size_t)ksgb * 16384;
        short8 bh0 = *(const short8*)(bp0 + boff);
        short8 bl0 = *(const short8*)(bp0 + 1024 + boff);

        for (int tap = 0; tap < 81; ++tap) {
            // prefetch next tap's B frags (L2-resident)
            int kn = ksgb + tap + 1; if (kn > 323) kn = 323;
            const char* bpn = wfb + (size_t)kn * 16384;
            short8 bh1 = *(const short8*)(bpn + boff);
            short8 bl1 = *(const short8*)(bpn + 1024 + boff);

            const int kh = tap / 9, kw = tap - kh * 9;
            const int toff = (kh * 22 + kw) * RS;
#pragma unroll
            for (int i = 0; i < MTC; ++i) {
                const int a = am[i] + toff;
                short8 Ah = *(const short8*)(Xs + a);
                short8 Al = *(const short8*)(Xs + a + 16);
                acc[i] = __builtin_amdgcn_mfma_f32_32x32x16_bf16(Ah, bh0, acc[i], 0, 0, 0);
                acc[i] = __builtin_amdgcn_mfma_f32_32x32x16_bf16(Ah, bl0, acc[i], 0, 0, 0);
                acc[i] = __builtin_amdgcn_mfma_f32_32x32x16_bf16(Al, bh0, acc[i], 0, 0, 0);
                acc[i] = __builtin_amdgcn_mfma_f32_32x32x16_bf16(Al, bl0, acc[i], 0, 0, 0);
            }
            bh0 = bh1; bl0 = bl1;
        }
    }

    // epilogue: bias + relu, NHWC store (C/D: col=lane&31, row=(r&3)+8*(r>>2)+4*(lane>>5))
#pragma unroll
    for (int i = 0; i < MTC; ++i) {
#pragma unroll
        for (int r = 0; r < 16; ++r) {
            int p = (mtbase + i) * 32 + (r & 3) + ((r >> 2) << 3) + kg * 4;
            if (p < 196) {
                float v = acc[i][r] + bias;
                c1o[((size_t)il * 196 + p) * 256 + co] = fmaxf(v, 0.f);
            }
        }
    }
}

__global__ __launch_bounds__(512, 4) void conv1_mfma_kernel(
    const float* __restrict__ x, const unsigned short* __restrict__ wf,
    const float* __restrict__ b1, float* __restrict__ c1o, int c0)
{
    __shared__ __align__(16) unsigned short Xs[484 * RS];
    const int t  = threadIdx.x;
    const int il = blockIdx.x >> 1;
    const int nb = blockIdx.x & 1;
    const int bg = c0 + il;
    const int w  = t >> 6;
    const int ncol = nb * 4 + (w & 3);
    if (w < 4) conv1_body<4>(Xs, x, wf, b1, c1o, bg, il, t, 0, ncol);
    else       conv1_body<3>(Xs, x, wf, b1, c1o, bg, il, t, 4, ncol);
}

// ---------------- primary caps conv via split-bf16 MFMA ----------------
#define PC_RS 36

__global__ __launch_bounds__(256, 2) void pc_mfma_kernel(
    const float* __restrict__ c1o, const unsigned short* __restrict__ pcwf,
    const float* __restrict__ pcb, float* __restrict__ pco)
{
    __shared__ unsigned short Xh[196 * PC_RS];
    __shared__ unsigned short Xl[196 * PC_RS];
    const int t  = threadIdx.x;
    const int l  = t & 63;
    const int w  = t >> 6;
    const int il = blockIdx.x;
    const int pos = l & 15;           // A row
    const int kg  = l >> 4;           // k-group 0..3
    const int oh = pos >> 2, ow = pos & 3;
    const char* wb = (const char*)pcwf;

    f32x4 acc0 = (f32x4)(0.f), acc1 = (f32x4)(0.f), acc2 = (f32x4)(0.f);

    for (int cc = 0; cc < 8; ++cc) {
        __syncthreads();
        for (int q = t; q < 1568; q += 256) {          // 196 px * 8 float4
            int p  = q >> 3;
            int c4 = (q & 7) << 2;
            const float4 v = *(const float4*)(c1o + ((size_t)il * 196 + p) * 256 + cc * 32 + c4);
            short4v hv, lv;
#pragma unroll
            for (int e = 0; e < 4; ++e) {
                float xv = ((const float*)&v)[e];
                unsigned short hi = bf16_rne(xv);
                hv[e] = (short)hi;
                lv[e] = (short)bf16_rne(xv - bf16_to_f(hi));
            }
            *(short4v*)(Xh + p * PC_RS + c4) = hv;
            *(short4v*)(Xl + p * PC_RS + c4) = lv;
        }
        __syncthreads();

        short8 Bh0[3], Bl0[3], Bh1[3], Bl1[3];
        {
            const char* bp = wb + ((size_t)(cc * 64 + w) * 6) * 1024 + l * 16;
#pragma unroll
            for (int ct = 0; ct < 3; ++ct) {
                Bh0[ct] = *(const short8*)(bp + ct * 2048);
                Bl0[ct] = *(const short8*)(bp + ct * 2048 + 1024);
            }
        }
        for (int tt = 0; tt < 16; ++tt) {
            const int tap = tt * 4 + w;
            const int tapn = (tt == 15) ? tap : (tap + 4);
            const char* bpn = wb + ((size_t)(cc * 64 + tapn) * 6) * 1024 + l * 16;
#pragma unroll
            for (int ct = 0; ct < 3; ++ct) {
                Bh1[ct] = *(const short8*)(bpn + ct * 2048);
                Bl1[ct] = *(const short8*)(bpn + ct * 2048 + 1024);
            }
            const int kh = tap >> 3, kw = tap & 7;
            const int pix = (2 * oh + kh) * 14 + (2 * ow + kw);
            const int a = pix * PC_RS + kg * 8;
            short4v h0 = *(const short4v*)(Xh + a);
            short4v h1 = *(const short4v*)(Xh + a + 4);
            short4v q0 = *(const short4v*)(Xl + a);
            short4v q1 = *(const short4v*)(Xl + a + 4);
            short8 Ah = __builtin_shufflevector(h0, h1, 0, 1, 2, 3, 4, 5, 6, 7);
            short8 Al = __builtin_shufflevector(q0, q1, 0, 1, 2, 3, 4, 5, 6, 7);

            acc0 = __builtin_amdgcn_mfma_f32_16x16x32_bf16(Ah, Bh0[0], acc0, 0, 0, 0);
            acc0 = __builtin_amdgcn_mfma_f32_16x16x32_bf16(Ah, Bl0[0], acc0, 0, 0, 0);
            acc0 = __builtin_amdgcn_mfma_f32_16x16x32_bf16(Al, Bh0[0], acc0, 0, 0, 0);
            acc0 = __builtin_amdgcn_mfma_f32_16x16x32_bf16(Al, Bl0[0], acc0, 0, 0, 0);
            acc1 = __builtin_amdgcn_mfma_f32_16x16x32_bf16(Ah, Bh0[1], acc1, 0, 0, 0);
            acc1 = __builtin_amdgcn_mfma_f32_16x16x32_bf16(Ah, Bl0[1], acc1, 0, 0, 0);
            acc1 = __builtin_amdgcn_mfma_f32_16x16x32_bf16(Al, Bh0[1], acc1, 0, 0, 0);
            acc1 = __builtin_amdgcn_mfma_f32_16x16x32_bf16(Al, Bl0[1], acc1, 0, 0, 0);
            acc2 = __builtin_amdgcn_mfma_f32_16x16x32_bf16(Ah, Bh0[2], acc2, 0, 0, 0);
            acc2 = __builtin_amdgcn_mfma_f32_16x16x32_bf16(Ah, Bl0[2], acc2, 0, 0, 0);
            acc2 = __builtin_amdgcn_mfma_f32_16x16x32_bf16(Al, Bh0[2], acc2, 0, 0, 0);
            acc2 = __builtin_amdgcn_mfma_f32_16x16x32_bf16(Al, Bl0[2], acc2, 0, 0, 0);
#pragma unroll
            for (int ct = 0; ct < 3; ++ct) { Bh0[ct] = Bh1[ct]; Bl0[ct] = Bl1[ct]; }
        }
    }

    __syncthreads();
    float* R = (float*)Xh;
#pragma unroll
    for (int ct = 0; ct < 3; ++ct) {
        f32x4 a = (ct == 0) ? acc0 : (ct == 1) ? acc1 : acc2;
#pragma unroll
        for (int r = 0; r < 4; ++r)
            R[(((w * 3 + ct) * 64) + l) * 4 + r] = a[r];
    }
    __syncthreads();
    for (int idx = t; idx < 768; idx += 256) {
        int pp = idx & 15, co = idx >> 4;
        int ct = co >> 4, col = co & 15;
        int lane = ((pp >> 2) << 4) | col, reg = pp & 3;
        float s = 0.f;
#pragma unroll
        for (int w4 = 0; w4 < 4; ++w4)
            s += R[(((w4 * 3 + ct) * 64) + lane) * 4 + reg];
        pco[(size_t)il * 768 + idx] = s + pcb[co];
    }
}

// ---------------- capsule squash + u_hat + routing + logits + mask ----------------
__global__ __launch_bounds__(64) void caps_kernel(
    const float* __restrict__ pco, const float* __restrict__ Wd,
    float* __restrict__ logits_out, float* __restrict__ hbuf, int c0) {
    __shared__ float u_s[96][8];
    __shared__ float uh[2][96][16];
    __shared__ float vv[2][16];
    __shared__ float cc2[2][96];
    __shared__ float lg_s[2];
    const int t = threadIdx.x;
    const int il = blockIdx.x;

    for (int cap = t; cap < 96; cap += 64) {
        float xr[8];
        float n2 = 0.f;
#pragma unroll
        for (int k = 0; k < 8; ++k) {
            xr[k] = pco[(size_t)il * 768 + cap * 8 + k];
            n2 = fmaf(xr[k], xr[k], n2);
        }
        float nr = sqrtf(n2);
        float sc = tanhf(nr) / (nr + 1e-8f);
#pragma unroll
        for (int k = 0; k < 8; ++k) u_s[cap][k] = xr[k] * sc;
    }
    __syncthreads();
    for (int j = t; j < 3072; j += 64) {
        int d = j & 15;
        int oi = j >> 4;           // o*96 + i
        int i = oi % 96;
        int o = oi / 96;
        float acc = 0.f;
#pragma unroll
        for (int k = 0; k < 8; ++k)
            acc = fmaf(Wd[(size_t)j * 8 + k], u_s[i][k], acc);
        uh[o][i][d] = acc;
    }
    __syncthreads();
    const int o = t >> 4, d = t & 15;
    if (t < 32) {
        float s = 0.f;
        for (int i = 0; i < 96; ++i) s += 0.5f * uh[o][i][d];
        float n2 = s * s;
        n2 += __shfl_xor(n2, 1); n2 += __shfl_xor(n2, 2);
        n2 += __shfl_xor(n2, 4); n2 += __shfl_xor(n2, 8);
        float nr = sqrtf(n2);
        vv[o][d] = tanhf(nr) * s / (nr + 1e-8f);
    }
    __syncthreads();
    for (int j = t; j < 192; j += 64) {
        int oo = j / 96, ii = j - oo * 96;
        float bsum = 0.f;
#pragma unroll
        for (int dd = 0; dd < 16; ++dd)
            bsum = fmaf(uh[oo][ii][dd], vv[oo][dd], bsum);
        cc2[oo][ii] = bsum;
    }
    __syncthreads();
    for (int ii = t; ii < 96; ii += 64) {
        float b0 = cc2[0][ii], b1v = cc2[1][ii];
        float m = fmaxf(b0, b1v);
        float e0 = expf(b0 - m), e1 = expf(b1v - m);
        float inv = 1.f / (e0 + e1);
        cc2[0][ii] = e0 * inv;
        cc2[1][ii] = e1 * inv;
    }
    __syncthreads();
    if (t < 32) {
        float s = 0.f;
        for (int i = 0; i < 96; ++i) s = fmaf(cc2[o][i], uh[o][i][d], s);
        float n2 = s * s;
        n2 += __shfl_xor(n2, 1); n2 += __shfl_xor(n2, 2);
        n2 += __shfl_xor(n2, 4); n2 += __shfl_xor(n2, 8);
        float nr = sqrtf(n2);
        float v = tanhf(nr) * s / (nr + 1e-8f);
        float n2v = v * v;
        n2v += __shfl_xor(n2v, 1); n2v += __shfl_xor(n2v, 2);
        n2v += __shfl_xor(n2v, 4); n2v += __shfl_xor(n2v, 8);
        vv[o][d] = v;
        if (d == 0) {
            float lg = sqrtf(n2v);
            lg_s[o] = lg;
            logits_out[(size_t)(c0 + il) * 2 + o] = lg;
        }
    }
    __syncthreads();
    if (t < 32) {
        int ostar = (lg_s[1] > lg_s[0]) ? 1 : 0;
        hbuf[(size_t)il * 32 + t] = (o == ostar) ? vv[o][d] : 0.f;
    }
}

// ---------------- decoder FC: out = act(in @ W^T + b) ----------------
__global__ __launch_bounds__(256) void fc_kernel(
    const float* __restrict__ in, const float* __restrict__ W,
    const float* __restrict__ bias, float* __restrict__ out,
    int M, int N, int K, int act) {
    __shared__ float As[64][33];
    __shared__ float Bs[64][33];
    const int t = threadIdx.x;
    const int m0 = blockIdx.x * 64, n0 = blockIdx.y * 64;
    const int tn = t & 15, tm = t >> 4;
    float acc[4][4];
#pragma unroll
    for (int i = 0; i < 4; ++i)
#pragma unroll
        for (int j = 0; j < 4; ++j) acc[i][j] = 0.f;
    const int rr = t >> 2, c8 = (t & 3) * 8;
    for (int kc = 0; kc < K; kc += 32) {
        __syncthreads();
        const int mrow = m0 + rr;
#pragma unroll
        for (int q = 0; q < 8; ++q) {
            As[rr][c8 + q] = (mrow < M) ? in[(size_t)mrow * K + kc + c8 + q] : 0.f;
            Bs[rr][c8 + q] = W[(size_t)(n0 + rr) * K + kc + c8 + q];
        }
        __syncthreads();
#pragma unroll
        for (int k = 0; k < 32; ++k) {
            float av[4], bv[4];
#pragma unroll
            for (int i = 0; i < 4; ++i) av[i] = As[tm * 4 + i][k];
#pragma unroll
            for (int j = 0; j < 4; ++j) bv[j] = Bs[tn * 4 + j][k];
#pragma unroll
            for (int i = 0; i < 4; ++i)
#pragma unroll
                for (int j = 0; j < 4; ++j) acc[i][j] = fmaf(av[i], bv[j], acc[i][j]);
        }
    }
#pragma unroll
    for (int i = 0; i < 4; ++i) {
        int m = m0 + tm * 4 + i;
        if (m < M) {
#pragma unroll
            for (int j = 0; j < 4; ++j) {
                int nn = n0 + tn * 4 + j;
                float v = acc[i][j] + bias[nn];
                if (act == 0) v = fmaxf(v, 0.f);
                else v = 1.f / (1.f + expf(-v));
                out[(size_t)m * N + nn] = v;
            }
        }
    }
}

// ---------------- host ----------------
extern "C" void kernel_launch(void* const* d_in, const int* in_sizes, int n_in,
                              void* d_out, int out_size, void* d_ws, size_t ws_size,
                              hipStream_t stream) {
    const float* x    = (const float*)d_in[0];
    const float* w1   = (const float*)d_in[1];
    const float* b1   = (const float*)d_in[2];
    const float* pcw  = (const float*)d_in[3];
    const float* pcb  = (const float*)d_in[4];
    const float* Wd   = (const float*)d_in[5];
    const float* dw1  = (const float*)d_in[6];
    const float* db1  = (const float*)d_in[7];
    const float* dw2  = (const float*)d_in[8];
    const float* db2  = (const float*)d_in[9];
    const float* dw3  = (const float*)d_in[10];
    const float* db3  = (const float*)d_in[11];
    float* out = (float*)d_out;

    const int B = 2048;
    float* ws = (float*)d_ws;
    unsigned short* wf = (unsigned short*)ws;                // 2,654,208 u16
    unsigned short* pcwf = (unsigned short*)(ws + 1327104);  // 1,572,864 u16
    float* dyn  = ws + 1327104 + 786432;

    const long long base_floats = 1327104LL + 786432LL;
    const long long per_img = 50176 + 768 + 32 + 512 + 1024;   // 52,512 floats/img
    long long avail = (long long)(ws_size / 4) - base_floats;
    int CH;
    if (avail < per_img) CH = 1;
    else CH = (int)(avail / per_img);
    if (CH > B) CH = B;

    reorder_wf_kernel<<<(324 * 8 * 64 * 8 + 255) / 256, 256, 0, stream>>>(w1, wf);
    reorder_pcwf_kernel<<<(1572864 + 255) / 256, 256, 0, stream>>>(pcw, pcwf);

    float* c1o  = dyn;
    float* pco  = c1o  + (size_t)CH * 50176;
    float* hbuf = pco  + (size_t)CH * 768;
    float* h1   = hbuf + (size_t)CH * 32;
    float* h2   = h1   + (size_t)CH * 512;

    for (int c0 = 0; c0 < B; c0 += CH) {
        int n = B - c0; if (n > CH) n = CH;
        conv1_mfma_kernel<<<n * 2, 512, 0, stream>>>(x, wf, b1, c1o, c0);
        pc_mfma_kernel<<<n, 256, 0, stream>>>(c1o, pcwf, pcb, pco);
        caps_kernel<<<n, 64, 0, stream>>>(pco, Wd, out, hbuf, c0);
        fc_kernel<<<dim3((n + 63) / 64, 8),  256, 0, stream>>>(hbuf, dw1, db1, h1, n, 512, 32, 0);
        fc_kernel<<<dim3((n + 63) / 64, 16), 256, 0, stream>>>(h1,   dw2, db2, h2, n, 1024, 512, 0);
        fc_kernel<<<dim3((n + 63) / 64, 4),  256, 0, stream>>>(h2,   dw3, db3, out + 4096 + (size_t)c0 * 256, n, 256, 1024, 1);
    }
}

// Round 10
// 3133.186 us; speedup vs baseline: 1.3198x; 1.3052x over previous
//
#include <hip/hip_runtime.h>
#include <cstdint>
#include <cstddef>

typedef short short8 __attribute__((ext_vector_type(8)));
typedef short short4v __attribute__((ext_vector_type(4)));
typedef float f32x16 __attribute__((ext_vector_type(16)));
typedef float f32x4 __attribute__((ext_vector_type(4)));

__device__ inline unsigned short bf16_rne(float x) {
    unsigned u = __float_as_uint(x);
    unsigned r = u + 0x7FFFu + ((u >> 16) & 1u);
    return (unsigned short)(r >> 16);
}
__device__ inline float bf16_to_f(unsigned short h) {
    return __uint_as_float(((unsigned)h) << 16);
}

// ---------------- weight reorders ----------------
// conv1_w (256,64,9,9) -> MFMA-fragment-order split-bf16 planes (32x32x16):
// wf[(ksg*8 + nc)*1024 u16]: [0..511]=hi frag, [512..1023]=lo frag
// ksg = cc*81 + tap (cc = 16-ci chunk) ; ci = cc*16 + (l>>5)*8 + j ; co = nc*32 + (l&31)
__global__ void reorder_wf_kernel(const float* __restrict__ w, unsigned short* __restrict__ wf) {
    int idx = blockIdx.x * 256 + threadIdx.x;      // over 324*8*64*8 = 1,327,104
    if (idx >= 324 * 8 * 64 * 8) return;
    int j   = idx & 7;
    int l   = (idx >> 3) & 63;
    int nc  = (idx >> 9) & 7;
    int ksg = idx >> 12;                           // 0..323
    int cc  = ksg / 81;
    int tap = ksg - cc * 81;
    int ci  = cc * 16 + ((l >> 5) << 3) + j;
    int co  = nc * 32 + (l & 31);
    float v = w[(co * 64 + ci) * 81 + tap];
    unsigned short hi = bf16_rne(v);
    unsigned short lo = bf16_rne(v - bf16_to_f(hi));
    size_t base = ((size_t)(ksg * 8 + nc)) * 1024;
    wf[base + l * 8 + j]       = hi;
    wf[base + 512 + l * 8 + j] = lo;
}

// pc_w (48,256,8,8) -> MFMA-fragment-order split-bf16 (16x16x32):
// dims [cc=8][tap=64][ct=3][plane=2][l=64][j=8] u16
__global__ void reorder_pcwf_kernel(const float* __restrict__ w, unsigned short* __restrict__ wf) {
    int idx = blockIdx.x * 256 + threadIdx.x;      // over 1,572,864
    if (idx >= 1572864) return;
    int j     = idx & 7;
    int l     = (idx >> 3) & 63;
    int plane = (idx >> 9) & 1;
    int rest  = idx >> 10;
    int ct    = rest % 3;
    int rest2 = rest / 3;
    int tap   = rest2 & 63;
    int cc    = rest2 >> 6;
    int co = ct * 16 + (l & 15);
    int ci = cc * 32 + ((l >> 4) << 3) + j;
    float v = w[((size_t)co * 256 + ci) * 64 + tap];
    unsigned short hi = bf16_rne(v);
    unsigned short out = plane ? bf16_rne(v - bf16_to_f(hi)) : hi;
    wf[idx] = out;
}

// ---------------- conv1 via split-bf16 MFMA (3-pass: hh + hl + lh) ----------------
// per image: M=196px (7 tiles of 32, padded), N=256co, K=5184 (4 ci-chunks x 81 taps x 16)
// block = 512 thr = 8 waves = 8 n-cols of 32 co ; grid = n images
// LDS: Xs[484][40] u16 = 38,720 B : per row [hi ci0-15][lo ci0-15][pad 8] -> 16B-aligned b128 frags
#define RS 40

__global__ __launch_bounds__(512, 1) void conv1_mfma_kernel(
    const float* __restrict__ x, const unsigned short* __restrict__ wf,
    const float* __restrict__ b1, float* __restrict__ c1o, int c0)
{
    __shared__ __align__(16) unsigned short Xs[484 * RS];
    const int t  = threadIdx.x;
    const int l  = t & 63;
    const int w  = t >> 6;            // wave = ncol 0..7
    const int il = blockIdx.x;
    const int bg = c0 + il;
    const int lane31 = l & 31;
    const int kg = l >> 5;
    const int co = w * 32 + lane31;
    const float bias = b1[co];

    int am[7];
#pragma unroll
    for (int mt = 0; mt < 7; ++mt) {
        int p  = mt * 32 + lane31;
        int pp = (p < 196) ? p : 0;      // clamp pad rows into valid LDS
        int oh = pp / 14, ow = pp - oh * 14;
        am[mt] = (oh * 22 + ow) * RS + kg * 8;
    }
    const char* wfb = (const char*)wf;
    const int boff = w * 2048 + l * 16;

    const int sidx = t >> 2;          // staging pixel row (+128/round)
    const int sblk = t & 3;           // staging ci block (4 ci)

    f32x16 acc[7];
#pragma unroll
    for (int mt = 0; mt < 7; ++mt) acc[mt] = (f32x16)(0.f);

    // prologue: stage cc=0 (gather-transpose, vector LDS writes)
#pragma unroll
    for (int r = 0; r < 4; ++r) {
        int s = sidx + r * 128;
        if (s < 484) {
            short4v hv, lv;
#pragma unroll
            for (int e = 0; e < 4; ++e) {
                float xv = x[((size_t)bg * 64 + sblk * 4 + e) * 484 + s];
                unsigned short hi = bf16_rne(xv);
                hv[e] = (short)hi;
                lv[e] = (short)bf16_rne(xv - bf16_to_f(hi));
            }
            *(short4v*)(Xs + s * RS + sblk * 4)      = hv;
            *(short4v*)(Xs + s * RS + 16 + sblk * 4) = lv;
        }
    }
    __syncthreads();

    for (int cc = 0; cc < 4; ++cc) {
        // issue next chunk's global loads early; latency hides under the 81 taps
        float vx[4][4];
        if (cc < 3) {
#pragma unroll
            for (int r = 0; r < 4; ++r) {
                int s = sidx + r * 128;
                if (s < 484) {
#pragma unroll
                    for (int e = 0; e < 4; ++e)
                        vx[r][e] = x[((size_t)bg * 64 + (cc + 1) * 16 + sblk * 4 + e) * 484 + s];
                }
            }
        }

        const int ksgb = cc * 81;
        short8 bh0 = *(const short8*)(wfb + (size_t)ksgb * 16384 + boff);
        short8 bl0 = *(const short8*)(wfb + (size_t)ksgb * 16384 + 1024 + boff);

        for (int tap = 0; tap < 81; ++tap) {
            // prefetch next tap's B frags (L2-resident)
            int kn = ksgb + tap + 1; if (kn > 323) kn = 323;
            short8 bh1 = *(const short8*)(wfb + (size_t)kn * 16384 + boff);
            short8 bl1 = *(const short8*)(wfb + (size_t)kn * 16384 + 1024 + boff);

            const int kh = tap / 9, kw = tap - kh * 9;
            const int toff = (kh * 22 + kw) * RS;
#pragma unroll
            for (int mt = 0; mt < 7; ++mt) {
                const int a = am[mt] + toff;
                short8 Ah = *(const short8*)(Xs + a);
                short8 Al = *(const short8*)(Xs + a + 16);
                acc[mt] = __builtin_amdgcn_mfma_f32_32x32x16_bf16(Ah, bh0, acc[mt], 0, 0, 0);
                acc[mt] = __builtin_amdgcn_mfma_f32_32x32x16_bf16(Ah, bl0, acc[mt], 0, 0, 0);
                acc[mt] = __builtin_amdgcn_mfma_f32_32x32x16_bf16(Al, bh0, acc[mt], 0, 0, 0);
                // 3-pass split: xl*wl term (<=2^-18 |x||w|) dropped — see R10 notes
            }
            bh0 = bh1; bl0 = bl1;
        }

        if (cc < 3) {
            __syncthreads();          // all waves done reading Xs for this cc
#pragma unroll
            for (int r = 0; r < 4; ++r) {
                int s = sidx + r * 128;
                if (s < 484) {
                    short4v hv, lv;
#pragma unroll
                    for (int e = 0; e < 4; ++e) {
                        float xv = vx[r][e];
                        unsigned short hi = bf16_rne(xv);
                        hv[e] = (short)hi;
                        lv[e] = (short)bf16_rne(xv - bf16_to_f(hi));
                    }
                    *(short4v*)(Xs + s * RS + sblk * 4)      = hv;
                    *(short4v*)(Xs + s * RS + 16 + sblk * 4) = lv;
                }
            }
            __syncthreads();
        }
    }

    // epilogue: bias + relu, NHWC store (C/D: col=lane&31, row=(r&3)+8*(r>>2)+4*(lane>>5))
#pragma unroll
    for (int mt = 0; mt < 7; ++mt) {
#pragma unroll
        for (int r = 0; r < 16; ++r) {
            int p = mt * 32 + (r & 3) + ((r >> 2) << 3) + kg * 4;
            if (p < 196) {
                float v = acc[mt][r] + bias;
                c1o[((size_t)il * 196 + p) * 256 + co] = fmaxf(v, 0.f);
            }
        }
    }
}

// ---------------- primary caps conv via split-bf16 MFMA ----------------
#define PC_RS 36

__global__ __launch_bounds__(256, 2) void pc_mfma_kernel(
    const float* __restrict__ c1o, const unsigned short* __restrict__ pcwf,
    const float* __restrict__ pcb, float* __restrict__ pco)
{
    __shared__ unsigned short Xh[196 * PC_RS];
    __shared__ unsigned short Xl[196 * PC_RS];
    const int t  = threadIdx.x;
    const int l  = t & 63;
    const int w  = t >> 6;
    const int il = blockIdx.x;
    const int pos = l & 15;           // A row
    const int kg  = l >> 4;           // k-group 0..3
    const int oh = pos >> 2, ow = pos & 3;
    const char* wb = (const char*)pcwf;

    f32x4 acc0 = (f32x4)(0.f), acc1 = (f32x4)(0.f), acc2 = (f32x4)(0.f);

    for (int cc = 0; cc < 8; ++cc) {
        __syncthreads();
        for (int q = t; q < 1568; q += 256) {          // 196 px * 8 float4
            int p  = q >> 3;
            int c4 = (q & 7) << 2;
            const float4 v = *(const float4*)(c1o + ((size_t)il * 196 + p) * 256 + cc * 32 + c4);
            short4v hv, lv;
#pragma unroll
            for (int e = 0; e < 4; ++e) {
                float xv = ((const float*)&v)[e];
                unsigned short hi = bf16_rne(xv);
                hv[e] = (short)hi;
                lv[e] = (short)bf16_rne(xv - bf16_to_f(hi));
            }
            *(short4v*)(Xh + p * PC_RS + c4) = hv;
            *(short4v*)(Xl + p * PC_RS + c4) = lv;
        }
        __syncthreads();

        short8 Bh0[3], Bl0[3], Bh1[3], Bl1[3];
        {
            const char* bp = wb + ((size_t)(cc * 64 + w) * 6) * 1024 + l * 16;
#pragma unroll
            for (int ct = 0; ct < 3; ++ct) {
                Bh0[ct] = *(const short8*)(bp + ct * 2048);
                Bl0[ct] = *(const short8*)(bp + ct * 2048 + 1024);
            }
        }
        for (int tt = 0; tt < 16; ++tt) {
            const int tap = tt * 4 + w;
            const int tapn = (tt == 15) ? tap : (tap + 4);
            const char* bpn = wb + ((size_t)(cc * 64 + tapn) * 6) * 1024 + l * 16;
#pragma unroll
            for (int ct = 0; ct < 3; ++ct) {
                Bh1[ct] = *(const short8*)(bpn + ct * 2048);
                Bl1[ct] = *(const short8*)(bpn + ct * 2048 + 1024);
            }
            const int kh = tap >> 3, kw = tap & 7;
            const int pix = (2 * oh + kh) * 14 + (2 * ow + kw);
            const int a = pix * PC_RS + kg * 8;
            short4v h0 = *(const short4v*)(Xh + a);
            short4v h1 = *(const short4v*)(Xh + a + 4);
            short4v q0 = *(const short4v*)(Xl + a);
            short4v q1 = *(const short4v*)(Xl + a + 4);
            short8 Ah = __builtin_shufflevector(h0, h1, 0, 1, 2, 3, 4, 5, 6, 7);
            short8 Al = __builtin_shufflevector(q0, q1, 0, 1, 2, 3, 4, 5, 6, 7);

            acc0 = __builtin_amdgcn_mfma_f32_16x16x32_bf16(Ah, Bh0[0], acc0, 0, 0, 0);
            acc0 = __builtin_amdgcn_mfma_f32_16x16x32_bf16(Ah, Bl0[0], acc0, 0, 0, 0);
            acc0 = __builtin_amdgcn_mfma_f32_16x16x32_bf16(Al, Bh0[0], acc0, 0, 0, 0);
            acc0 = __builtin_amdgcn_mfma_f32_16x16x32_bf16(Al, Bl0[0], acc0, 0, 0, 0);
            acc1 = __builtin_amdgcn_mfma_f32_16x16x32_bf16(Ah, Bh0[1], acc1, 0, 0, 0);
            acc1 = __builtin_amdgcn_mfma_f32_16x16x32_bf16(Ah, Bl0[1], acc1, 0, 0, 0);
            acc1 = __builtin_amdgcn_mfma_f32_16x16x32_bf16(Al, Bh0[1], acc1, 0, 0, 0);
            acc1 = __builtin_amdgcn_mfma_f32_16x16x32_bf16(Al, Bl0[1], acc1, 0, 0, 0);
            acc2 = __builtin_amdgcn_mfma_f32_16x16x32_bf16(Ah, Bh0[2], acc2, 0, 0, 0);
            acc2 = __builtin_amdgcn_mfma_f32_16x16x32_bf16(Ah, Bl0[2], acc2, 0, 0, 0);
            acc2 = __builtin_amdgcn_mfma_f32_16x16x32_bf16(Al, Bh0[2], acc2, 0, 0, 0);
            acc2 = __builtin_amdgcn_mfma_f32_16x16x32_bf16(Al, Bl0[2], acc2, 0, 0, 0);
#pragma unroll
            for (int ct = 0; ct < 3; ++ct) { Bh0[ct] = Bh1[ct]; Bl0[ct] = Bl1[ct]; }
        }
    }

    __syncthreads();
    float* R = (float*)Xh;
#pragma unroll
    for (int ct = 0; ct < 3; ++ct) {
        f32x4 a = (ct == 0) ? acc0 : (ct == 1) ? acc1 : acc2;
#pragma unroll
        for (int r = 0; r < 4; ++r)
            R[(((w * 3 + ct) * 64) + l) * 4 + r] = a[r];
    }
    __syncthreads();
    for (int idx = t; idx < 768; idx += 256) {
        int pp = idx & 15, co = idx >> 4;
        int ct = co >> 4, col = co & 15;
        int lane = ((pp >> 2) << 4) | col, reg = pp & 3;
        float s = 0.f;
#pragma unroll
        for (int w4 = 0; w4 < 4; ++w4)
            s += R[(((w4 * 3 + ct) * 64) + lane) * 4 + reg];
        pco[(size_t)il * 768 + idx] = s + pcb[co];
    }
}

// ---------------- capsule squash + u_hat + routing + logits + mask ----------------
__global__ __launch_bounds__(64) void caps_kernel(
    const float* __restrict__ pco, const float* __restrict__ Wd,
    float* __restrict__ logits_out, float* __restrict__ hbuf, int c0) {
    __shared__ float u_s[96][8];
    __shared__ float uh[2][96][16];
    __shared__ float vv[2][16];
    __shared__ float cc2[2][96];
    __shared__ float lg_s[2];
    const int t = threadIdx.x;
    const int il = blockIdx.x;

    for (int cap = t; cap < 96; cap += 64) {
        float xr[8];
        float n2 = 0.f;
#pragma unroll
        for (int k = 0; k < 8; ++k) {
            xr[k] = pco[(size_t)il * 768 + cap * 8 + k];
            n2 = fmaf(xr[k], xr[k], n2);
        }
        float nr = sqrtf(n2);
        float sc = tanhf(nr) / (nr + 1e-8f);
#pragma unroll
        for (int k = 0; k < 8; ++k) u_s[cap][k] = xr[k] * sc;
    }
    __syncthreads();
    for (int j = t; j < 3072; j += 64) {
        int d = j & 15;
        int oi = j >> 4;           // o*96 + i
        int i = oi % 96;
        int o = oi / 96;
        float acc = 0.f;
#pragma unroll
        for (int k = 0; k < 8; ++k)
            acc = fmaf(Wd[(size_t)j * 8 + k], u_s[i][k], acc);
        uh[o][i][d] = acc;
    }
    __syncthreads();
    const int o = t >> 4, d = t & 15;
    if (t < 32) {
        float s = 0.f;
        for (int i = 0; i < 96; ++i) s += 0.5f * uh[o][i][d];
        float n2 = s * s;
        n2 += __shfl_xor(n2, 1); n2 += __shfl_xor(n2, 2);
        n2 += __shfl_xor(n2, 4); n2 += __shfl_xor(n2, 8);
        float nr = sqrtf(n2);
        vv[o][d] = tanhf(nr) * s / (nr + 1e-8f);
    }
    __syncthreads();
    for (int j = t; j < 192; j += 64) {
        int oo = j / 96, ii = j - oo * 96;
        float bsum = 0.f;
#pragma unroll
        for (int dd = 0; dd < 16; ++dd)
            bsum = fmaf(uh[oo][ii][dd], vv[oo][dd], bsum);
        cc2[oo][ii] = bsum;
    }
    __syncthreads();
    for (int ii = t; ii < 96; ii += 64) {
        float b0 = cc2[0][ii], b1v = cc2[1][ii];
        float m = fmaxf(b0, b1v);
        float e0 = expf(b0 - m), e1 = expf(b1v - m);
        float inv = 1.f / (e0 + e1);
        cc2[0][ii] = e0 * inv;
        cc2[1][ii] = e1 * inv;
    }
    __syncthreads();
    if (t < 32) {
        float s = 0.f;
        for (int i = 0; i < 96; ++i) s = fmaf(cc2[o][i], uh[o][i][d], s);
        float n2 = s * s;
        n2 += __shfl_xor(n2, 1); n2 += __shfl_xor(n2, 2);
        n2 += __shfl_xor(n2, 4); n2 += __shfl_xor(n2, 8);
        float nr = sqrtf(n2);
        float v = tanhf(nr) * s / (nr + 1e-8f);
        float n2v = v * v;
        n2v += __shfl_xor(n2v, 1); n2v += __shfl_xor(n2v, 2);
        n2v += __shfl_xor(n2v, 4); n2v += __shfl_xor(n2v, 8);
        vv[o][d] = v;
        if (d == 0) {
            float lg = sqrtf(n2v);
            lg_s[o] = lg;
            logits_out[(size_t)(c0 + il) * 2 + o] = lg;
        }
    }
    __syncthreads();
    if (t < 32) {
        int ostar = (lg_s[1] > lg_s[0]) ? 1 : 0;
        hbuf[(size_t)il * 32 + t] = (o == ostar) ? vv[o][d] : 0.f;
    }
}

// ---------------- decoder FC: out = act(in @ W^T + b) ----------------
__global__ __launch_bounds__(256) void fc_kernel(
    const float* __restrict__ in, const float* __restrict__ W,
    const float* __restrict__ bias, float* __restrict__ out,
    int M, int N, int K, int act) {
    __shared__ float As[64][33];
    __shared__ float Bs[64][33];
    const int t = threadIdx.x;
    const int m0 = blockIdx.x * 64, n0 = blockIdx.y * 64;
    const int tn = t & 15, tm = t >> 4;
    float acc[4][4];
#pragma unroll
    for (int i = 0; i < 4; ++i)
#pragma unroll
        for (int j = 0; j < 4; ++j) acc[i][j] = 0.f;
    const int rr = t >> 2, c8 = (t & 3) * 8;
    for (int kc = 0; kc < K; kc += 32) {
        __syncthreads();
        const int mrow = m0 + rr;
#pragma unroll
        for (int q = 0; q < 8; ++q) {
            As[rr][c8 + q] = (mrow < M) ? in[(size_t)mrow * K + kc + c8 + q] : 0.f;
            Bs[rr][c8 + q] = W[(size_t)(n0 + rr) * K + kc + c8 + q];
        }
        __syncthreads();
#pragma unroll
        for (int k = 0; k < 32; ++k) {
            float av[4], bv[4];
#pragma unroll
            for (int i = 0; i < 4; ++i) av[i] = As[tm * 4 + i][k];
#pragma unroll
            for (int j = 0; j < 4; ++j) bv[j] = Bs[tn * 4 + j][k];
#pragma unroll
            for (int i = 0; i < 4; ++i)
#pragma unroll
                for (int j = 0; j < 4; ++j) acc[i][j] = fmaf(av[i], bv[j], acc[i][j]);
        }
    }
#pragma unroll
    for (int i = 0; i < 4; ++i) {
        int m = m0 + tm * 4 + i;
        if (m < M) {
#pragma unroll
            for (int j = 0; j < 4; ++j) {
                int nn = n0 + tn * 4 + j;
                float v = acc[i][j] + bias[nn];
                if (act == 0) v = fmaxf(v, 0.f);
                else v = 1.f / (1.f + expf(-v));
                out[(size_t)m * N + nn] = v;
            }
        }
    }
}

// ---------------- host ----------------
extern "C" void kernel_launch(void* const* d_in, const int* in_sizes, int n_in,
                              void* d_out, int out_size, void* d_ws, size_t ws_size,
                              hipStream_t stream) {
    const float* x    = (const float*)d_in[0];
    const float* w1   = (const float*)d_in[1];
    const float* b1   = (const float*)d_in[2];
    const float* pcw  = (const float*)d_in[3];
    const float* pcb  = (const float*)d_in[4];
    const float* Wd   = (const float*)d_in[5];
    const float* dw1  = (const float*)d_in[6];
    const float* db1  = (const float*)d_in[7];
    const float* dw2  = (const float*)d_in[8];
    const float* db2  = (const float*)d_in[9];
    const float* dw3  = (const float*)d_in[10];
    const float* db3  = (const float*)d_in[11];
    float* out = (float*)d_out;

    const int B = 2048;
    float* ws = (float*)d_ws;
    unsigned short* wf = (unsigned short*)ws;                // 2,654,208 u16
    unsigned short* pcwf = (unsigned short*)(ws + 1327104);  // 1,572,864 u16
    float* dyn  = ws + 1327104 + 786432;

    const long long base_floats = 1327104LL + 786432LL;
    const long long per_img = 50176 + 768 + 32 + 512 + 1024;   // 52,512 floats/img
    long long avail = (long long)(ws_size / 4) - base_floats;
    int CH;
    if (avail < per_img) CH = 1;
    else CH = (int)(avail / per_img);
    if (CH > B) CH = B;

    reorder_wf_kernel<<<(324 * 8 * 64 * 8 + 255) / 256, 256, 0, stream>>>(w1, wf);
    reorder_pcwf_kernel<<<(1572864 + 255) / 256, 256, 0, stream>>>(pcw, pcwf);

    float* c1o  = dyn;
    float* pco  = c1o  + (size_t)CH * 50176;
    float* hbuf = pco  + (size_t)CH * 768;
    float* h1   = hbuf + (size_t)CH * 32;
    float* h2   = h1   + (size_t)CH * 512;

    for (int c0 = 0; c0 < B; c0 += CH) {
        int n = B - c0; if (n > CH) n = CH;
        conv1_mfma_kernel<<<n, 512, 0, stream>>>(x, wf, b1, c1o, c0);
        pc_mfma_kernel<<<n, 256, 0, stream>>>(c1o, pcwf, pcb, pco);
        caps_kernel<<<n, 64, 0, stream>>>(pco, Wd, out, hbuf, c0);
        fc_kernel<<<dim3((n + 63) / 64, 8),  256, 0, stream>>>(hbuf, dw1, db1, h1, n, 512, 32, 0);
        fc_kernel<<<dim3((n + 63) / 64, 16), 256, 0, stream>>>(h1,   dw2, db2, h2, n, 1024, 512, 0);
        fc_kernel<<<dim3((n + 63) / 64, 4),  256, 0, stream>>>(h2,   dw3, db3, out + 4096 + (size_t)c0 * 256, n, 256, 1024, 1);
    }
}